// Round 3
// baseline (258.710 us; speedup 1.0000x reference)
//
#include <hip/hip_runtime.h>
#include <math.h>

typedef __attribute__((ext_vector_type(8))) short short8;
typedef __attribute__((ext_vector_type(4))) float float4v;
typedef unsigned int uint;

#define BATCH 8
#define SEQ   4096
#define DIM   768
#define HID   512
#define M_TOK (BATCH * SEQ)   // 32768

// ---------- helpers ----------
static __device__ __forceinline__ short f2bf_rne(float x) {
    unsigned int u = __float_as_uint(x);
    unsigned int r = (u + 0x7FFFu + ((u >> 16) & 1u)) >> 16;   // RNE
    return (short)r;
}
// pack two floats -> 2 bf16 (truncate) in ONE v_perm_b32. lo=bf16(a), hi=bf16(b).
static __device__ __forceinline__ uint pack_bf2(float a, float b) {
    return __builtin_amdgcn_perm(__float_as_uint(b), __float_as_uint(a), 0x07060302u);
}
union FragU { uint u[4]; short8 s; };

// ---------- prep: transpose W1 -> W1T (bf16, [HID][DIM]) ----------
__global__ __launch_bounds__(256) void prep_kernel(const float* __restrict__ W1,
                                                   short* __restrict__ W1T) {
    int idx = blockIdx.x * 256 + threadIdx.x;        // 0 .. DIM*HID-1
    if (idx < DIM * HID) {
        int k = idx / HID, n = idx % HID;            // W1 row-major [DIM][HID]
        W1T[n * DIM + k] = f2bf_rne(W1[idx]);
    }
}

// ---------- MLP: partial[n_g][row] = sum over 128-col slice of relu(A.W1+b1)*W2 ----------
// A [M_TOK][DIM] fp32 loaded DIRECTLY into MFMA A-fragments (global->reg->pack, no LDS).
// B = W1^T [HID][DIM] bf16 staged in LDS (two 32-k panels, pad-40 layout).
// Tile 64M x 128N, BK=64 -> 12 iterations. Grid 2048. Wave = 16M x 128N.
// id map: 4 n-siblings of an m-tile land on ONE XCD, 8 ids apart (temporally co-resident).
__global__ __launch_bounds__(256) void mlp_kernel(const float* __restrict__ A,
                                                  const short* __restrict__ BT,
                                                  const float* __restrict__ b1,
                                                  const float* __restrict__ W2,
                                                  float* __restrict__ partial) {
    __shared__ short Bs[2 * 128 * 40];   // two 32-k panels, rows padded to 40 shorts

    const int id   = blockIdx.x;
    const int row8 = id & 7;               // XCD id under round-robin
    const int n_g  = (id >> 3) & 3;        // n-group: siblings 8 apart -> same XCD
    const int m_t  = (id >> 5) * 8 + row8;
    const int m0 = m_t * 64, n0 = n_g * 128;

    const int tid = threadIdx.x, wave = tid >> 6, lane = tid & 63;
    const int quad = lane >> 4, r = lane & 15;

    const float* aRow = A + (size_t)(m0 + wave * 16 + r) * DIM + quad * 8;
    const short* bRow = BT + (size_t)(n0 + (tid >> 1)) * DIM + (tid & 1) * 32;
    const int bwr = (tid & 1) * 5120 + (tid >> 1) * 40;   // shorts offset in Bs

    float4v fA[2][4];
    short8  fB[2][4];
#pragma unroll
    for (int i = 0; i < 4; i++) fB[0][i] = *(const short8*)(bRow + i * 8);
    fA[0][0] = *(const float4v*)(aRow + 0);
    fA[0][1] = *(const float4v*)(aRow + 4);
    fA[0][2] = *(const float4v*)(aRow + 32);
    fA[0][3] = *(const float4v*)(aRow + 36);

    float4v acc[8] = {};

#pragma unroll
    for (int it = 0; it < 12; ++it) {
        const int cur = it & 1;
        if (it < 11) {                       // prefetch next chunk into registers
            const float* ap = aRow + (it + 1) * 64;
            fA[cur ^ 1][0] = *(const float4v*)(ap + 0);
            fA[cur ^ 1][1] = *(const float4v*)(ap + 4);
            fA[cur ^ 1][2] = *(const float4v*)(ap + 32);
            fA[cur ^ 1][3] = *(const float4v*)(ap + 36);
            const short* bp = bRow + (it + 1) * 64;
#pragma unroll
            for (int i = 0; i < 4; i++) fB[cur ^ 1][i] = *(const short8*)(bp + i * 8);
        }
        __syncthreads();                     // previous iteration's Bs reads done
#pragma unroll
        for (int i = 0; i < 4; i++) *(short8*)(&Bs[bwr + i * 8]) = fB[cur][i];
        __syncthreads();                     // Bs ready

#pragma unroll
        for (int ks = 0; ks < 2; ks++) {
            FragU af;
            af.u[0] = pack_bf2(fA[cur][ks * 2][0], fA[cur][ks * 2][1]);
            af.u[1] = pack_bf2(fA[cur][ks * 2][2], fA[cur][ks * 2][3]);
            af.u[2] = pack_bf2(fA[cur][ks * 2 + 1][0], fA[cur][ks * 2 + 1][1]);
            af.u[3] = pack_bf2(fA[cur][ks * 2 + 1][2], fA[cur][ks * 2 + 1][3]);
#pragma unroll
            for (int j = 0; j < 8; j++) {
                short8 bf = *(const short8*)(&Bs[ks * 5120 + (j * 16 + r) * 40 + quad * 8]);
                acc[j] = __builtin_amdgcn_mfma_f32_16x16x32_bf16(af.s, bf, acc[j], 0, 0, 0);
            }
        }
    }

    // epilogue: h = relu(acc + b1); p(row) = sum over this 128-col slice of h*W2
    float b1v[8], w2v[8];
#pragma unroll
    for (int j = 0; j < 8; j++) {
        int gc = n0 + j * 16 + r;
        b1v[j] = b1[gc];
        w2v[j] = W2[gc];
    }
#pragma unroll
    for (int v = 0; v < 4; v++) {
        float p = 0.f;
#pragma unroll
        for (int j = 0; j < 8; j++) {
            float h = acc[j][v] + b1v[j];
            h = h > 0.f ? h : 0.f;
            p += h * w2v[j];
        }
#pragma unroll
        for (int off = 1; off < 16; off <<= 1) p += __shfl_xor(p, off, 64);
        if (r == 0)
            partial[(size_t)n_g * M_TOK + m0 + wave * 16 + quad * 4 + v] = p;
    }
}

// ---------- bits: logits -> hard bits (64-bit masks) + per-block counts ----------
__global__ __launch_bounds__(256) void bits_kernel(const float* __restrict__ partial,
                                                   const float* __restrict__ b2p,
                                                   const float* __restrict__ noise,
                                                   unsigned long long* __restrict__ bits,
                                                   int* __restrict__ counts) {
    const int blk = blockIdx.x;                  // 64 blocks: 8 per batch
    const int tid = threadIdx.x, wid = tid >> 6, lane = tid & 63;
    const float b2 = b2p[0];
    __shared__ int pc[8];
    const int base = blk * 512;                  // flattened token base
#pragma unroll
    for (int h = 0; h < 2; h++) {
        int l = base + h * 256 + tid;
        float u = noise[l];
        float lg = b2 + logf(u) - log1pf(-u);
#pragma unroll
        for (int q = 0; q < 4; q++) lg += partial[(size_t)q * M_TOK + l];
        unsigned long long bal = __ballot(lg > 0.f);
        if (lane == 0) {
            bits[blk * 8 + h * 4 + wid] = bal;
            pc[h * 4 + wid] = __popcll(bal);
        }
    }
    __syncthreads();
    if (tid == 0) {
        int s = 0;
        for (int i = 0; i < 8; i++) s += pc[i];
        counts[blk] = s;
    }
}

// ---------- starts: rank boundaries within batch -> segment start offsets ----------
__global__ __launch_bounds__(256) void starts_kernel(const unsigned long long* __restrict__ bits,
                                                     const int* __restrict__ counts,
                                                     int* __restrict__ starts,
                                                     int* __restrict__ nseg) {
    const int blk = blockIdx.x, b = blk >> 3, s8 = blk & 7;
    const int tid = threadIdx.x, wid = tid >> 6, lane = tid & 63;
    __shared__ int cs[9];
    __shared__ unsigned long long ms[8];
    if (tid == 0) {
        int s = 0;
        for (int i = 0; i < 8; i++) { cs[i] = s; s += counts[b * 8 + i]; }
        cs[8] = s;
    }
    if (tid < 8) ms[tid] = bits[blk * 8 + tid];
    __syncthreads();
    const int blockoff = cs[s8];
#pragma unroll
    for (int h = 0; h < 2; h++) {
        int j = h * 4 + wid;
        unsigned long long mask = ms[j];
        if (!((mask >> lane) & 1ULL)) continue;
        int pre = blockoff;
        for (int i = 0; i < j; i++) pre += __popcll(ms[i]);
        pre += __popcll(lane ? (mask & (~0ULL >> (64 - lane))) : 0ULL);
        int lb = s8 * 512 + j * 64 + lane;       // token index within batch
        int run = pre + 1;
        if (lb < SEQ - 1) starts[b * (SEQ + 1) + run] = lb + 1;
    }
    if (s8 == 7 && tid == 0) {
        int nb = cs[8];
        int lastbit = (int)(ms[7] >> 63) & 1;
        int ns = nb + (lastbit ? 0 : 1);
        starts[b * (SEQ + 1)] = 0;
        starts[b * (SEQ + 1) + ns] = SEQ;
        nseg[b] = ns;
    }
}

// ---------- pool: 4 waves/block, one wave per segment slot; zero-fill unused slots ----------
__global__ __launch_bounds__(256) void pool_kernel(const float* __restrict__ hidden,
                                                   const int* __restrict__ starts,
                                                   const int* __restrict__ nseg,
                                                   float* __restrict__ out) {
    const int wid = threadIdx.x >> 6, lane = threadIdx.x & 63;
    const int s = blockIdx.x * 4 + wid, b = blockIdx.y;
    float* orow = out + (size_t)(b * SEQ + s) * DIM;
    const int ns = nseg[b];
    if (s >= ns) {
        float4v z = {0.f, 0.f, 0.f, 0.f};
        *(float4v*)(orow + lane * 4)         = z;
        *(float4v*)(orow + (lane + 64) * 4)  = z;
        *(float4v*)(orow + (lane + 128) * 4) = z;
        return;
    }
    const int st = starts[b * (SEQ + 1) + s];
    const int en = starts[b * (SEQ + 1) + s + 1];
    float4v a0 = {0.f, 0.f, 0.f, 0.f}, a1 = a0, a2 = a0;
    const float* hbase = hidden + (size_t)(b * SEQ) * DIM;
    for (int row = st; row < en; row++) {
        const float* hr = hbase + (size_t)row * DIM;
        a0 += *(const float4v*)(hr + lane * 4);
        a1 += *(const float4v*)(hr + (lane + 64) * 4);
        a2 += *(const float4v*)(hr + (lane + 128) * 4);
    }
    const float invc = 1.f / (float)(en - st);
    a0 *= invc; a1 *= invc; a2 *= invc;
    *(float4v*)(orow + lane * 4)         = a0;
    *(float4v*)(orow + (lane + 64) * 4)  = a1;
    *(float4v*)(orow + (lane + 128) * 4) = a2;
}

// ---------- finalize: loss / num_boundaries / total_positions ----------
__global__ void finalize_kernel(const int* __restrict__ counts, float* __restrict__ tail) {
    int nb = 0;
    for (int i = 0; i < 64; i++) nb += counts[i];
    float ratio = (float)nb / (float)M_TOK;
    float d = fabsf(ratio - 0.25f) - 0.05f;    // PRIOR + 0.05 = 0.25, margin 0.05
    tail[0] = d > 0.f ? d : 0.f;
    tail[1] = (float)nb;
    tail[2] = (float)M_TOK;
}

// ---------- launch ----------
extern "C" void kernel_launch(void* const* d_in, const int* in_sizes, int n_in,
                              void* d_out, int out_size, void* d_ws, size_t ws_size,
                              hipStream_t stream) {
    const float* hidden = (const float*)d_in[0];
    const float* W1     = (const float*)d_in[1];
    const float* b1     = (const float*)d_in[2];
    const float* W2     = (const float*)d_in[3];
    const float* b2     = (const float*)d_in[4];
    const float* noise  = (const float*)d_in[5];

    char* ws = (char*)d_ws;
    short* W1T     = (short*)(ws);                           // 786432 B
    float* partial = (float*)(ws + 786432);                  // 4*32768*4 = 524288 B
    int*   starts  = (int*)(ws + 1310720);                   // 8*4097*4  = 131104 B
    unsigned long long* bits = (unsigned long long*)(ws + 1441824);   // 512*8 = 4096 B
    int*   counts  = (int*)(ws + 1445920);                   // 64*4
    int*   nseg    = (int*)(ws + 1446176);                   // 8*4
    float* out     = (float*)d_out;

    prep_kernel<<<1536, 256, 0, stream>>>(W1, W1T);
    mlp_kernel<<<2048, 256, 0, stream>>>(hidden, W1T, b1, W2, partial);
    bits_kernel<<<64, 256, 0, stream>>>(partial, b2, noise, bits, counts);
    starts_kernel<<<64, 256, 0, stream>>>(bits, counts, starts, nseg);
    pool_kernel<<<dim3(SEQ / 4, BATCH), 256, 0, stream>>>(hidden, starts, nseg, out);
    finalize_kernel<<<1, 1, 0, stream>>>(counts, out + (size_t)M_TOK * DIM);
}